// Round 2
// baseline (4805.880 us; speedup 1.0000x reference)
//
#include <hip/hip_runtime.h>
#include <hip/hip_bf16.h>

typedef __attribute__((ext_vector_type(8))) short short8;
typedef __attribute__((ext_vector_type(4))) float f32x4;

static constexpr int NNODE = 8192;
static constexpr int NEDGE = 262144;
static constexpr int NBATCH = 16;
static constexpr int TDIM = 15;
static constexpr int G1D = 32;
static constexpr int G2D = 64;
static constexpr size_t NG2 = (size_t)NNODE * G2D;  // 524288

// ---------------- graph preprocessing ----------------

__global__ void deg_cnt_kernel(const int* __restrict__ ei, int* __restrict__ deg,
                               int* __restrict__ cnt) {
    int e = blockIdx.x * 256 + threadIdx.x;
    if (e < NEDGE) {
        atomicAdd(&deg[ei[e]], 1);           // row (out-degree per reference)
        atomicAdd(&cnt[ei[NEDGE + e]], 1);   // col (CSR bucket counts)
    }
}

__global__ void dinv_kernel(const int* __restrict__ deg, float* __restrict__ dinv) {
    int n = blockIdx.x * 256 + threadIdx.x;
    if (n < NNODE) dinv[n] = (deg[n] > 0) ? rsqrtf((float)deg[n]) : 0.f;
}

__global__ __launch_bounds__(1024) void scan_kernel(const int* __restrict__ cnt,
                                                    int* __restrict__ ptr) {
    __shared__ int s[1024];
    int t = threadIdx.x;
    int base = t * 8;
    int loc[8];
    int sum = 0;
#pragma unroll
    for (int i = 0; i < 8; ++i) { loc[i] = sum; sum += cnt[base + i]; }
    s[t] = sum;
    __syncthreads();
    for (int off = 1; off < 1024; off <<= 1) {
        int v = (t >= off) ? s[t - off] : 0;
        __syncthreads();
        s[t] += v;
        __syncthreads();
    }
    int prev = (t > 0) ? s[t - 1] : 0;
#pragma unroll
    for (int i = 0; i < 8; ++i) ptr[base + i] = prev + loc[i];
    if (t == 1023) ptr[NNODE] = s[1023];
}

__global__ void fill_kernel(const int* __restrict__ ei, const int* __restrict__ ptr,
                            int* __restrict__ fill, const float* __restrict__ dinv,
                            int* __restrict__ csr_src, float* __restrict__ csr_w) {
    int e = blockIdx.x * 256 + threadIdx.x;
    if (e < NEDGE) {
        int r = ei[e], c = ei[NEDGE + e];
        int pos = ptr[c] + atomicAdd(&fill[c], 1);
        csr_src[pos] = r;
        csr_w[pos] = -dinv[r] * dinv[c];
    }
}

// ---------------- FFT (real part = cosine transform) ----------------

__global__ __launch_bounds__(256) void fft_kernel(const float* __restrict__ x,
                                                  float* __restrict__ T0) {
    int n = blockIdx.x;
    __shared__ float xl[NBATCH * TDIM];   // 240
    __shared__ float ct[TDIM * TDIM];     // 225
    int t = threadIdx.x;
    if (t < NBATCH * TDIM) {
        int b = t / TDIM, s = t % TDIM;
        xl[t] = x[((size_t)b * NNODE + n) * TDIM + s];
    }
    if (t < TDIM * TDIM) {
        int tt = t / TDIM, s = t % TDIM;
        ct[t] = cosf(6.283185307179586f * (float)((tt * s) % TDIM) / 15.0f);
    }
    __syncthreads();
    if (t < NBATCH * TDIM) {
        int b = t / TDIM, f = t % TDIM;
        float a = 0.f;
#pragma unroll
        for (int s = 0; s < TDIM; ++s) a += xl[b * TDIM + s] * ct[f * TDIM + s];
        T0[(size_t)n * (NBATCH * TDIM) + t] = a;
    }
}

// ---------------- W^T bf16 (zero-padded K=32) ----------------
// Wt[k][g][f], f in [0,32)

__global__ void wt_kernel(const float* __restrict__ W, unsigned short* __restrict__ Wt,
                          int F, int G, int total) {
    int i = blockIdx.x * 256 + threadIdx.x;
    if (i < total) {
        int f = i & 31;
        int g = (i >> 5) % G;
        int k = i / (32 * G);
        float v = (f < F) ? W[((size_t)k * F + f) * G + g] : 0.f;
        __hip_bfloat16 h = __float2bfloat16(v);
        Wt[i] = *reinterpret_cast<unsigned short*>(&h);
    }
}

// ---------------- fused Chebyshev step ----------------
// block = destination node. Gathers Lhat(T1)[c] (or Lhat(T0) if FIRST), forms
// T2 = 2*gather - T0 (or T1 = gather if FIRST), writes T2, then
// OUT[c] (+)= T2row @ W_k via mfma_f32_16x16x32_bf16 (fp32 accum).

template <int F, int G, bool FIRST>
__global__ __launch_bounds__(256) void cheb_kernel(
    const float* __restrict__ T0, const float* __restrict__ T1,
    float* __restrict__ T2, float* __restrict__ OUT,
    const int* __restrict__ cptr, const int* __restrict__ csrc,
    const float* __restrict__ cw, const unsigned short* __restrict__ Wt,
    const float* __restrict__ bias) {
    constexpr int BF = NBATCH * F;
    constexpr int PE = (BF + 255) / 256;
    __shared__ float t2f[BF];
    __shared__ unsigned short abf[2][16][32];
    __shared__ int es[256];
    __shared__ float ews[256];

    const int c = blockIdx.x;
    const int tid = threadIdx.x;
    const float* __restrict__ Tsrc = FIRST ? T0 : T1;

    float acc[PE];
#pragma unroll
    for (int q = 0; q < PE; ++q) acc[q] = 0.f;

    const int p0 = cptr[c], p1 = cptr[c + 1];
    for (int base = p0; base < p1; base += 256) {
        int m = p1 - base;
        if (m > 256) m = 256;
        __syncthreads();
        if (tid < m) { es[tid] = csrc[base + tid]; ews[tid] = cw[base + tid]; }
        __syncthreads();
        for (int j = 0; j < m; ++j) {
            const float* zs = Tsrc + (size_t)es[j] * BF;
            const float w = ews[j];
#pragma unroll
            for (int q = 0; q < PE; ++q) {
                const int idx = tid + q * 256;
                if (idx < BF) acc[q] += w * zs[idx];
            }
        }
    }

#pragma unroll
    for (int q = 0; q < PE; ++q) {
        const int idx = tid + q * 256;
        if (idx < BF) {
            float v = FIRST ? acc[q] : (2.f * acc[q] - T0[(size_t)c * BF + idx]);
            t2f[idx] = v;
            T2[(size_t)c * BF + idx] = v;
        }
    }
    __syncthreads();

    // bf16 A-operand staging: 16 rows x 32 cols = 512 entries, 256 threads ->
    // stride loop (the round-0 bug: `if (tid<512)` left rows 8..15 as LDS
    // garbage -> NaN / absmax 3328).
    for (int s = tid; s < 512; s += 256) {
        const int b = s >> 5, f = s & 31;
        float v0 = (f < F) ? t2f[b * F + f] : 0.f;
        __hip_bfloat16 h0 = __float2bfloat16(v0);
        abf[0][b][f] = *reinterpret_cast<unsigned short*>(&h0);
        if (FIRST) {
            float v1 = (f < F) ? T0[(size_t)c * BF + b * F + f] : 0.f;
            __hip_bfloat16 h1 = __float2bfloat16(v1);
            abf[1][b][f] = *reinterpret_cast<unsigned short*>(&h1);
        }
    }
    __syncthreads();

    const int wv = tid >> 6, lane = tid & 63;
    constexpr int GT = G / 16;
    if (wv < GT) {
        const int m0 = lane & 15;       // A row (b) and B col (g within tile)
        const int krow = lane >> 4;
        const int k0 = krow * 8;        // k base for this lane's 8 elements
        const int g = wv * 16 + m0;
        float* outrow = OUT + (size_t)c * (16 * G);
        short8 aCur = *reinterpret_cast<const short8*>(&abf[0][m0][k0]);
        f32x4 d;
        if (FIRST) {
            const float bb = bias[g];
            d = (f32x4){bb, bb, bb, bb};
            short8 aT0 = *reinterpret_cast<const short8*>(&abf[1][m0][k0]);
            short8 b0 = *reinterpret_cast<const short8*>(&Wt[(size_t)g * 32 + k0]);
            short8 b1 = *reinterpret_cast<const short8*>(&Wt[(size_t)(G + g) * 32 + k0]);
            d = __builtin_amdgcn_mfma_f32_16x16x32_bf16(aT0, b0, d, 0, 0, 0);
            d = __builtin_amdgcn_mfma_f32_16x16x32_bf16(aCur, b1, d, 0, 0, 0);
        } else {
            short8 bk = *reinterpret_cast<const short8*>(&Wt[(size_t)g * 32 + k0]);
#pragma unroll
            for (int r = 0; r < 4; ++r) d[r] = outrow[(krow * 4 + r) * G + g];
            d = __builtin_amdgcn_mfma_f32_16x16x32_bf16(aCur, bk, d, 0, 0, 0);
        }
#pragma unroll
        for (int r = 0; r < 4; ++r) outrow[(krow * 4 + r) * G + g] = d[r];
    }
}

// ---------------- relu / transpose / fc ----------------

__global__ void relu_kernel(float* __restrict__ p, int n) {
    int i = blockIdx.x * 256 + threadIdx.x;
    if (i < n) p[i] = fmaxf(p[i], 0.f);
}

// OUT2[n][b][g] -> Hflat[b][n*G2+g], with relu
__global__ void relu_tr_kernel(const float* __restrict__ OUT2, float* __restrict__ Hflat) {
    size_t i = (size_t)blockIdx.x * 256 + threadIdx.x;  // over 8192*16*64
    int g = (int)(i & 63);
    int b = (int)((i >> 6) & 15);
    int n = (int)(i >> 10);
    float v = fmaxf(OUT2[i], 0.f);
    Hflat[(size_t)b * NG2 + (size_t)n * G2D + g] = v;
}

// grid = 128 chunks * 32 cgroups; block = 512 (8 waves); wave handles 2 c's.
__global__ __launch_bounds__(512) void fc1_kernel(const float* __restrict__ Hflat,
                                                  const float* __restrict__ fc1w,
                                                  float* __restrict__ partial) {
    int wave = threadIdx.x >> 6, lane = threadIdx.x & 63;
    int chunk = blockIdx.x & 127, cg = blockIdx.x >> 7;
    int c0 = (cg * 8 + wave) * 2;
    const float* w0 = fc1w + (size_t)c0 * NG2 + (size_t)chunk * 4096;
    const float* w1 = w0 + NG2;
    const float* h = Hflat + (size_t)chunk * 4096;
    float a0[16], a1[16];
#pragma unroll
    for (int b = 0; b < 16; ++b) { a0[b] = 0.f; a1[b] = 0.f; }
    for (int it = 0; it < 16; ++it) {
        int j = it * 256 + lane * 4;
        float4 wv0 = *reinterpret_cast<const float4*>(w0 + j);
        float4 wv1 = *reinterpret_cast<const float4*>(w1 + j);
#pragma unroll
        for (int b = 0; b < 16; ++b) {
            float4 hv = *reinterpret_cast<const float4*>(h + (size_t)b * NG2 + j);
            a0[b] += wv0.x * hv.x + wv0.y * hv.y + wv0.z * hv.z + wv0.w * hv.w;
            a1[b] += wv1.x * hv.x + wv1.y * hv.y + wv1.z * hv.z + wv1.w * hv.w;
        }
    }
#pragma unroll
    for (int b = 0; b < 16; ++b) {
        float v0 = a0[b], v1 = a1[b];
        for (int off = 32; off; off >>= 1) {
            v0 += __shfl_down(v0, off);
            v1 += __shfl_down(v1, off);
        }
        if (lane == 0) {
            partial[((size_t)chunk * 512 + c0) * 16 + b] = v0;
            partial[((size_t)chunk * 512 + c0 + 1) * 16 + b] = v1;
        }
    }
}

__global__ void fc1_reduce_kernel(const float* __restrict__ partial,
                                  const float* __restrict__ fc1b, float* __restrict__ h1) {
    int i = blockIdx.x * 256 + threadIdx.x;  // 512*16
    if (i < 512 * 16) {
        int b = i & 15, c = i >> 4;
        float s = fc1b[c];
        for (int ch = 0; ch < 128; ++ch) s += partial[((size_t)ch * 512 + c) * 16 + b];
        h1[b * 512 + c] = s;
    }
}

__global__ __launch_bounds__(1024) void fc2_kernel(const float* __restrict__ h1,
                                                   const float* __restrict__ fc2w,
                                                   const float* __restrict__ fc2b,
                                                   float* __restrict__ out) {
    __shared__ float z[16][8];
    int wave = threadIdx.x >> 6, lane = threadIdx.x & 63;  // wave = b
    for (int d = 0; d < 6; ++d) {
        float acc = 0.f;
        for (int c = lane; c < 512; c += 64) acc += h1[wave * 512 + c] * fc2w[d * 512 + c];
        for (int off = 32; off; off >>= 1) acc += __shfl_down(acc, off);
        if (lane == 0) z[wave][d] = acc + fc2b[d];
    }
    __syncthreads();
    int t = threadIdx.x;
    if (t < 96) {
        int b = t / 6, d = t % 6;
        float m = z[b][0];
#pragma unroll
        for (int j = 1; j < 6; ++j) m = fmaxf(m, z[b][j]);
        float se = 0.f;
#pragma unroll
        for (int j = 0; j < 6; ++j) se += expf(z[b][j] - m);
        out[b * 6 + d] = z[b][d] - m - logf(se);
    }
}

// ---------------- host ----------------

extern "C" void kernel_launch(void* const* d_in, const int* in_sizes, int n_in,
                              void* d_out, int out_size, void* d_ws, size_t ws_size,
                              hipStream_t stream) {
    const float* x = (const float*)d_in[0];
    const int* ei = (const int*)d_in[1];
    const float* W1 = (const float*)d_in[2];
    const float* b1 = (const float*)d_in[3];
    const float* W2 = (const float*)d_in[4];
    const float* b2 = (const float*)d_in[5];
    const float* fc1w = (const float*)d_in[6];
    const float* fc1b = (const float*)d_in[7];
    const float* fc2w = (const float*)d_in[8];
    const float* fc2b = (const float*)d_in[9];
    float* out = (float*)d_out;

    char* ws = (char*)d_ws;
    size_t o = 0;
    auto alloc = [&](size_t bytes) -> void* {
        void* p = ws + o;
        o += (bytes + 255) & ~(size_t)255;
        return p;
    };
    const size_t TBYTES = (size_t)NNODE * 512 * 4;  // max BF = 512
    float* Ta = (float*)alloc(TBYTES);
    float* Tb = (float*)alloc(TBYTES);
    float* Tc = (float*)alloc(TBYTES);
    float* OUT1 = (float*)alloc((size_t)NNODE * NBATCH * G1D * 4);
    float* OUT2 = (float*)alloc((size_t)NNODE * NBATCH * G2D * 4);
    int* deg = (int*)alloc(3 * NNODE * 4);
    int* cnt = deg + NNODE;
    int* fill = cnt + NNODE;
    int* cptr = (int*)alloc((NNODE + 8) * 4);
    float* dinv = (float*)alloc(NNODE * 4);
    int* csr_src = (int*)alloc((size_t)NEDGE * 4);
    float* csr_w = (float*)alloc((size_t)NEDGE * 4);
    unsigned short* Wt1 = (unsigned short*)alloc(25 * 32 * 32 * 2);
    unsigned short* Wt2 = (unsigned short*)alloc(25 * 64 * 32 * 2);
    float* h1 = (float*)alloc(16 * 512 * 4);
    // aliases (safe: used only after conv2 completes)
    float* Hflat = Ta;      // 33.55 MB spans Ta+Tb
    float* partial = Tc;    // 4.19 MB

    hipMemsetAsync(deg, 0, 3 * NNODE * 4, stream);
    deg_cnt_kernel<<<NEDGE / 256, 256, 0, stream>>>(ei, deg, cnt);
    dinv_kernel<<<NNODE / 256, 256, 0, stream>>>(deg, dinv);
    scan_kernel<<<1, 1024, 0, stream>>>(cnt, cptr);
    fill_kernel<<<NEDGE / 256, 256, 0, stream>>>(ei, cptr, fill, dinv, csr_src, csr_w);
    fft_kernel<<<NNODE, 256, 0, stream>>>(x, Ta);
    wt_kernel<<<(25 * 32 * 32) / 256, 256, 0, stream>>>(W1, Wt1, 15, 32, 25 * 32 * 32);
    wt_kernel<<<(25 * 64 * 32) / 256, 256, 0, stream>>>(W2, Wt2, 32, 64, 25 * 64 * 32);

    // conv1: x in Ta (stride 240)
    cheb_kernel<15, 32, true><<<NNODE, 256, 0, stream>>>(Ta, nullptr, Tb, OUT1, cptr,
                                                         csr_src, csr_w, Wt1, b1);
    {
        float* r0 = Ta; float* r1 = Tb; float* r2 = Tc;
        for (int k = 2; k < 25; ++k) {
            cheb_kernel<15, 32, false><<<NNODE, 256, 0, stream>>>(
                r0, r1, r2, OUT1, cptr, csr_src, csr_w, Wt1 + (size_t)k * 32 * 32, nullptr);
            float* t = r0; r0 = r1; r1 = r2; r2 = t;
        }
    }
    relu_kernel<<<(NNODE * 512) / 256, 256, 0, stream>>>(OUT1, NNODE * 512);

    // conv2: Tx0 = OUT1 (H), stride 512
    cheb_kernel<32, 64, true><<<NNODE, 256, 0, stream>>>(OUT1, nullptr, Ta, OUT2, cptr,
                                                         csr_src, csr_w, Wt2, b2);
    {
        // k=2: (OUT1, Ta) -> Tb, then cycle {Ta,Tb,Tc}
        cheb_kernel<32, 64, false><<<NNODE, 256, 0, stream>>>(
            OUT1, Ta, Tb, OUT2, cptr, csr_src, csr_w, Wt2 + (size_t)2 * 64 * 32, nullptr);
        float* q0 = Ta; float* q1 = Tb; float* q2 = Tc;
        for (int k = 3; k < 25; ++k) {
            cheb_kernel<32, 64, false><<<NNODE, 256, 0, stream>>>(
                q0, q1, q2, OUT2, cptr, csr_src, csr_w, Wt2 + (size_t)k * 64 * 32, nullptr);
            float* t = q0; q0 = q1; q1 = q2; q2 = t;
        }
    }

    relu_tr_kernel<<<(NNODE * NBATCH * G2D) / 256, 256, 0, stream>>>(OUT2, Hflat);
    fc1_kernel<<<128 * 32, 512, 0, stream>>>(Hflat, fc1w, partial);
    fc1_reduce_kernel<<<32, 256, 0, stream>>>(partial, fc1b, h1);
    fc2_kernel<<<1, 1024, 0, stream>>>(h1, fc2w, fc2b, out);
}

// Round 3
// 2094.676 us; speedup vs baseline: 2.2943x; 2.2943x over previous
//
#include <hip/hip_runtime.h>
#include <hip/hip_bf16.h>

typedef _Float16 f16x2 __attribute__((ext_vector_type(2)));
typedef _Float16 f16x8 __attribute__((ext_vector_type(8)));
typedef float f32x4 __attribute__((ext_vector_type(4)));

static constexpr int NNODE = 8192;
static constexpr int NEDGE = 262144;
static constexpr int NBATCH = 16;
static constexpr int TDIM = 15;
static constexpr int G1D = 32;
static constexpr int G2D = 64;
static constexpr size_t NG2 = (size_t)NNODE * G2D;  // 524288

// ---------------- graph preprocessing ----------------

__global__ void deg_cnt_kernel(const int* __restrict__ ei, int* __restrict__ deg,
                               int* __restrict__ cnt) {
    int e = blockIdx.x * 256 + threadIdx.x;
    if (e < NEDGE) {
        atomicAdd(&deg[ei[e]], 1);           // row (out-degree per reference)
        atomicAdd(&cnt[ei[NEDGE + e]], 1);   // col (CSR bucket counts)
    }
}

__global__ void dinv_kernel(const int* __restrict__ deg, float* __restrict__ dinv) {
    int n = blockIdx.x * 256 + threadIdx.x;
    if (n < NNODE) dinv[n] = (deg[n] > 0) ? rsqrtf((float)deg[n]) : 0.f;
}

__global__ __launch_bounds__(1024) void scan_kernel(const int* __restrict__ cnt,
                                                    int* __restrict__ ptr) {
    __shared__ int s[1024];
    int t = threadIdx.x;
    int base = t * 8;
    int loc[8];
    int sum = 0;
#pragma unroll
    for (int i = 0; i < 8; ++i) { loc[i] = sum; sum += cnt[base + i]; }
    s[t] = sum;
    __syncthreads();
    for (int off = 1; off < 1024; off <<= 1) {
        int v = (t >= off) ? s[t - off] : 0;
        __syncthreads();
        s[t] += v;
        __syncthreads();
    }
    int prev = (t > 0) ? s[t - 1] : 0;
#pragma unroll
    for (int i = 0; i < 8; ++i) ptr[base + i] = prev + loc[i];
    if (t == 1023) ptr[NNODE] = s[1023];
}

__global__ void fill_kernel(const int* __restrict__ ei, const int* __restrict__ ptr,
                            int* __restrict__ fill, const float* __restrict__ dinv,
                            int* __restrict__ csr_src, float* __restrict__ csr_w) {
    int e = blockIdx.x * 256 + threadIdx.x;
    if (e < NEDGE) {
        int r = ei[e], c = ei[NEDGE + e];
        int pos = ptr[c] + atomicAdd(&fill[c], 1);
        csr_src[pos] = r;
        csr_w[pos] = -dinv[r] * dinv[c];
    }
}

// ---------------- FFT (real part = cosine transform), fp16 out ----------------

__global__ __launch_bounds__(256) void fft_kernel(const float* __restrict__ x,
                                                  _Float16* __restrict__ T0) {
    int n = blockIdx.x;
    __shared__ float xl[NBATCH * TDIM];   // 240
    __shared__ float ct[TDIM * TDIM];     // 225
    int t = threadIdx.x;
    if (t < NBATCH * TDIM) {
        int b = t / TDIM, s = t % TDIM;
        xl[t] = x[((size_t)b * NNODE + n) * TDIM + s];
    }
    if (t < TDIM * TDIM) {
        int tt = t / TDIM, s = t % TDIM;
        ct[t] = cosf(6.283185307179586f * (float)((tt * s) % TDIM) / 15.0f);
    }
    __syncthreads();
    if (t < NBATCH * TDIM) {
        int b = t / TDIM, f = t % TDIM;
        float a = 0.f;
#pragma unroll
        for (int s = 0; s < TDIM; ++s) a += xl[b * TDIM + s] * ct[f * TDIM + s];
        T0[(size_t)n * (NBATCH * TDIM) + t] = (_Float16)a;
    }
}

// ---------------- W^T fp16 (zero-padded K=32): Wt[k][g][f0..31] ----------------

__global__ void wt_kernel(const float* __restrict__ W, _Float16* __restrict__ Wt,
                          int F, int G, int total) {
    int i = blockIdx.x * 256 + threadIdx.x;
    if (i < total) {
        int f = i & 31;
        int g = (i >> 5) % G;
        int k = i / (32 * G);
        float v = (f < F) ? W[((size_t)k * F + f) * G + g] : 0.f;
        Wt[i] = (_Float16)v;
    }
}

// ---------------- fused Chebyshev step (fp16 state) ----------------
// block = destination node c. Gathers Lhat(Tsrc)[c] (fp16 rows, fp32 accum),
// forms T2 = 2*gather - T0 (or T1 = gather if FIRST), writes fp16 T2, then
// OUT[c] (+)= T2row @ W_k via mfma_f32_16x16x32_f16.

template <int F, int G, bool FIRST>
__global__ __launch_bounds__(256) void cheb_kernel(
    const _Float16* __restrict__ T0, const _Float16* __restrict__ T1,
    _Float16* __restrict__ T2, float* __restrict__ OUT,
    const int* __restrict__ cptr, const int* __restrict__ csrc,
    const float* __restrict__ cw, const _Float16* __restrict__ Wt,
    const float* __restrict__ bias) {
    constexpr int BF = NBATCH * F;   // halfs per node row
    constexpr int DW = BF / 2;       // dwords per node row (120 or 256)
    __shared__ _Float16 t2h[BF];
    __shared__ _Float16 abf[2][16][32];
    __shared__ int es[256];
    __shared__ float ews[256];

    const int c = blockIdx.x;
    const int tid = threadIdx.x;
    const _Float16* __restrict__ Tsrc = FIRST ? T0 : T1;
    const f16x2* __restrict__ base = reinterpret_cast<const f16x2*>(Tsrc);

    float a0 = 0.f, a1 = 0.f;
    const int p0 = cptr[c], p1 = cptr[c + 1];
    for (int tb = p0; tb < p1; tb += 256) {
        int m = p1 - tb;
        if (m > 256) m = 256;
        __syncthreads();
        if (tid < m) { es[tid] = csrc[tb + tid]; ews[tid] = cw[tb + tid]; }
        __syncthreads();
        if (tid < DW) {
            int j = 0;
            // 4-deep pipelined gather: 4 independent 1-dword row loads in flight
            for (; j + 4 <= m; j += 4) {
                int s0 = es[j], s1 = es[j + 1], s2 = es[j + 2], s3 = es[j + 3];
                float w0 = ews[j], w1 = ews[j + 1], w2 = ews[j + 2], w3 = ews[j + 3];
                f16x2 r0 = base[(size_t)s0 * DW + tid];
                f16x2 r1 = base[(size_t)s1 * DW + tid];
                f16x2 r2 = base[(size_t)s2 * DW + tid];
                f16x2 r3 = base[(size_t)s3 * DW + tid];
                a0 += w0 * (float)r0[0]; a1 += w0 * (float)r0[1];
                a0 += w1 * (float)r1[0]; a1 += w1 * (float)r1[1];
                a0 += w2 * (float)r2[0]; a1 += w2 * (float)r2[1];
                a0 += w3 * (float)r3[0]; a1 += w3 * (float)r3[1];
            }
            for (; j < m; ++j) {
                int s = es[j]; float w = ews[j];
                f16x2 r = base[(size_t)s * DW + tid];
                a0 += w * (float)r[0]; a1 += w * (float)r[1];
            }
        }
    }

    if (tid < DW) {
        float v0 = a0, v1 = a1;
        if (!FIRST) {
            f16x2 t0v = reinterpret_cast<const f16x2*>(T0)[(size_t)c * DW + tid];
            v0 = 2.f * a0 - (float)t0v[0];
            v1 = 2.f * a1 - (float)t0v[1];
        }
        f16x2 o; o[0] = (_Float16)v0; o[1] = (_Float16)v1;
        reinterpret_cast<f16x2*>(T2)[(size_t)c * DW + tid] = o;
        t2h[2 * tid] = o[0];
        t2h[2 * tid + 1] = o[1];
    }
    __syncthreads();

    // stage A operands, zero-padded to K=32 (full 512-entry stride loop)
    for (int s = tid; s < 512; s += 256) {
        const int b = s >> 5, f = s & 31;
        abf[0][b][f] = (f < F) ? t2h[b * F + f] : (_Float16)0.f;
        if (FIRST)
            abf[1][b][f] = (f < F) ? T0[(size_t)c * BF + b * F + f] : (_Float16)0.f;
    }
    __syncthreads();

    const int wv = tid >> 6, lane = tid & 63;
    constexpr int GT = G / 16;
    if (wv < GT) {
        const int m0 = lane & 15;       // A row (b) / D col (g within tile)
        const int krow = lane >> 4;
        const int k0 = krow * 8;
        const int g = wv * 16 + m0;
        float* outrow = OUT + (size_t)c * (16 * G);
        f16x8 aCur = *reinterpret_cast<const f16x8*>(&abf[0][m0][k0]);
        f32x4 d;
        if (FIRST) {
            const float bb = bias[g];
            d = (f32x4){bb, bb, bb, bb};
            f16x8 aT0 = *reinterpret_cast<const f16x8*>(&abf[1][m0][k0]);
            f16x8 b0 = *reinterpret_cast<const f16x8*>(&Wt[(size_t)g * 32 + k0]);
            f16x8 b1 = *reinterpret_cast<const f16x8*>(&Wt[(size_t)(G + g) * 32 + k0]);
            d = __builtin_amdgcn_mfma_f32_16x16x32_f16(aT0, b0, d, 0, 0, 0);
            d = __builtin_amdgcn_mfma_f32_16x16x32_f16(aCur, b1, d, 0, 0, 0);
        } else {
            f16x8 bk = *reinterpret_cast<const f16x8*>(&Wt[(size_t)g * 32 + k0]);
#pragma unroll
            for (int r = 0; r < 4; ++r) d[r] = outrow[(krow * 4 + r) * G + g];
            d = __builtin_amdgcn_mfma_f32_16x16x32_f16(aCur, bk, d, 0, 0, 0);
        }
#pragma unroll
        for (int r = 0; r < 4; ++r) outrow[(krow * 4 + r) * G + g] = d[r];
    }
}

// ---------------- relu / transpose / fc ----------------

// OUT1 fp32 [n][16*32] -> relu -> fp16 T0 for conv2 (same layout)
__global__ void relu_mid_kernel(const float* __restrict__ OUT1,
                                _Float16* __restrict__ T0c) {
    int i = blockIdx.x * 256 + threadIdx.x;   // NNODE*512
    T0c[i] = (_Float16)fmaxf(OUT1[i], 0.f);
}

// OUT2[n][b][g] -> Hflat[b][n*G2+g], with relu
__global__ void relu_tr_kernel(const float* __restrict__ OUT2, float* __restrict__ Hflat) {
    size_t i = (size_t)blockIdx.x * 256 + threadIdx.x;  // over 8192*16*64
    int g = (int)(i & 63);
    int b = (int)((i >> 6) & 15);
    int n = (int)(i >> 10);
    float v = fmaxf(OUT2[i], 0.f);
    Hflat[(size_t)b * NG2 + (size_t)n * G2D + g] = v;
}

// grid = 128 chunks * 32 cgroups; block = 512 (8 waves); wave handles 2 c's.
__global__ __launch_bounds__(512) void fc1_kernel(const float* __restrict__ Hflat,
                                                  const float* __restrict__ fc1w,
                                                  float* __restrict__ partial) {
    int wave = threadIdx.x >> 6, lane = threadIdx.x & 63;
    int chunk = blockIdx.x & 127, cg = blockIdx.x >> 7;
    int c0 = (cg * 8 + wave) * 2;
    const float* w0 = fc1w + (size_t)c0 * NG2 + (size_t)chunk * 4096;
    const float* w1 = w0 + NG2;
    const float* h = Hflat + (size_t)chunk * 4096;
    float a0[16], a1[16];
#pragma unroll
    for (int b = 0; b < 16; ++b) { a0[b] = 0.f; a1[b] = 0.f; }
    for (int it = 0; it < 16; ++it) {
        int j = it * 256 + lane * 4;
        float4 wv0 = *reinterpret_cast<const float4*>(w0 + j);
        float4 wv1 = *reinterpret_cast<const float4*>(w1 + j);
#pragma unroll
        for (int b = 0; b < 16; ++b) {
            float4 hv = *reinterpret_cast<const float4*>(h + (size_t)b * NG2 + j);
            a0[b] += wv0.x * hv.x + wv0.y * hv.y + wv0.z * hv.z + wv0.w * hv.w;
            a1[b] += wv1.x * hv.x + wv1.y * hv.y + wv1.z * hv.z + wv1.w * hv.w;
        }
    }
#pragma unroll
    for (int b = 0; b < 16; ++b) {
        float v0 = a0[b], v1 = a1[b];
        for (int off = 32; off; off >>= 1) {
            v0 += __shfl_down(v0, off);
            v1 += __shfl_down(v1, off);
        }
        if (lane == 0) {
            partial[((size_t)chunk * 512 + c0) * 16 + b] = v0;
            partial[((size_t)chunk * 512 + c0 + 1) * 16 + b] = v1;
        }
    }
}

__global__ void fc1_reduce_kernel(const float* __restrict__ partial,
                                  const float* __restrict__ fc1b, float* __restrict__ h1) {
    int i = blockIdx.x * 256 + threadIdx.x;  // 512*16
    if (i < 512 * 16) {
        int b = i & 15, c = i >> 4;
        float s = fc1b[c];
        for (int ch = 0; ch < 128; ++ch) s += partial[((size_t)ch * 512 + c) * 16 + b];
        h1[b * 512 + c] = s;
    }
}

__global__ __launch_bounds__(1024) void fc2_kernel(const float* __restrict__ h1,
                                                   const float* __restrict__ fc2w,
                                                   const float* __restrict__ fc2b,
                                                   float* __restrict__ out) {
    __shared__ float z[16][8];
    int wave = threadIdx.x >> 6, lane = threadIdx.x & 63;  // wave = b
    for (int d = 0; d < 6; ++d) {
        float acc = 0.f;
        for (int c = lane; c < 512; c += 64) acc += h1[wave * 512 + c] * fc2w[d * 512 + c];
        for (int off = 32; off; off >>= 1) acc += __shfl_down(acc, off);
        if (lane == 0) z[wave][d] = acc + fc2b[d];
    }
    __syncthreads();
    int t = threadIdx.x;
    if (t < 96) {
        int b = t / 6, d = t % 6;
        float m = z[b][0];
#pragma unroll
        for (int j = 1; j < 6; ++j) m = fmaxf(m, z[b][j]);
        float se = 0.f;
#pragma unroll
        for (int j = 0; j < 6; ++j) se += expf(z[b][j] - m);
        out[b * 6 + d] = z[b][d] - m - logf(se);
    }
}

// ---------------- host ----------------

extern "C" void kernel_launch(void* const* d_in, const int* in_sizes, int n_in,
                              void* d_out, int out_size, void* d_ws, size_t ws_size,
                              hipStream_t stream) {
    const float* x = (const float*)d_in[0];
    const int* ei = (const int*)d_in[1];
    const float* W1 = (const float*)d_in[2];
    const float* b1 = (const float*)d_in[3];
    const float* W2 = (const float*)d_in[4];
    const float* b2 = (const float*)d_in[5];
    const float* fc1w = (const float*)d_in[6];
    const float* fc1b = (const float*)d_in[7];
    const float* fc2w = (const float*)d_in[8];
    const float* fc2b = (const float*)d_in[9];
    float* out = (float*)d_out;

    char* ws = (char*)d_ws;
    size_t o = 0;
    auto alloc = [&](size_t bytes) -> void* {
        void* p = ws + o;
        o += (bytes + 255) & ~(size_t)255;
        return p;
    };
    const size_t THALF = (size_t)NNODE * 512 * 2;  // fp16 T buffer (max BF=512)
    _Float16* T0a = (_Float16*)alloc((size_t)NNODE * 240 * 2);  // fft out
    _Float16* Ta = (_Float16*)alloc(THALF);
    _Float16* Tb = (_Float16*)alloc(THALF);
    _Float16* Tc = (_Float16*)alloc(THALF);
    _Float16* T0c = (_Float16*)alloc(THALF);                    // relu(OUT1) fp16
    float* OUT1 = (float*)alloc((size_t)NNODE * NBATCH * G1D * 4);
    float* OUT2 = (float*)alloc((size_t)NNODE * NBATCH * G2D * 4);
    float* Hflat = (float*)alloc((size_t)NBATCH * NG2 * 4);
    float* partial = (float*)alloc((size_t)128 * 512 * 16 * 4);
    int* deg = (int*)alloc(3 * NNODE * 4);
    int* cnt = deg + NNODE;
    int* fill = cnt + NNODE;
    int* cptr = (int*)alloc((NNODE + 8) * 4);
    float* dinv = (float*)alloc(NNODE * 4);
    int* csr_src = (int*)alloc((size_t)NEDGE * 4);
    float* csr_w = (float*)alloc((size_t)NEDGE * 4);
    _Float16* Wt1 = (_Float16*)alloc(25 * 32 * 32 * 2);
    _Float16* Wt2 = (_Float16*)alloc(25 * 64 * 32 * 2);
    float* h1 = (float*)alloc(16 * 512 * 4);

    hipMemsetAsync(deg, 0, 3 * NNODE * 4, stream);
    deg_cnt_kernel<<<NEDGE / 256, 256, 0, stream>>>(ei, deg, cnt);
    dinv_kernel<<<NNODE / 256, 256, 0, stream>>>(deg, dinv);
    scan_kernel<<<1, 1024, 0, stream>>>(cnt, cptr);
    fill_kernel<<<NEDGE / 256, 256, 0, stream>>>(ei, cptr, fill, dinv, csr_src, csr_w);
    fft_kernel<<<NNODE, 256, 0, stream>>>(x, T0a);
    wt_kernel<<<(25 * 32 * 32) / 256, 256, 0, stream>>>(W1, Wt1, 15, 32, 25 * 32 * 32);
    wt_kernel<<<(25 * 64 * 32) / 256, 256, 0, stream>>>(W2, Wt2, 32, 64, 25 * 64 * 32);

    // conv1 (F=15 -> BF=240 halfs)
    cheb_kernel<15, 32, true><<<NNODE, 256, 0, stream>>>(T0a, nullptr, Ta, OUT1, cptr,
                                                         csr_src, csr_w, Wt1, b1);
    cheb_kernel<15, 32, false><<<NNODE, 256, 0, stream>>>(
        T0a, Ta, Tb, OUT1, cptr, csr_src, csr_w, Wt1 + (size_t)2 * 32 * 32, nullptr);
    {
        _Float16 *r0 = Ta, *r1 = Tb, *r2 = Tc;
        for (int k = 3; k < 25; ++k) {
            cheb_kernel<15, 32, false><<<NNODE, 256, 0, stream>>>(
                r0, r1, r2, OUT1, cptr, csr_src, csr_w, Wt1 + (size_t)k * 32 * 32, nullptr);
            _Float16* t = r0; r0 = r1; r1 = r2; r2 = t;
        }
    }
    relu_mid_kernel<<<(NNODE * 512) / 256, 256, 0, stream>>>(OUT1, T0c);

    // conv2 (F=32 -> BF=512 halfs)
    cheb_kernel<32, 64, true><<<NNODE, 256, 0, stream>>>(T0c, nullptr, Ta, OUT2, cptr,
                                                         csr_src, csr_w, Wt2, b2);
    cheb_kernel<32, 64, false><<<NNODE, 256, 0, stream>>>(
        T0c, Ta, Tb, OUT2, cptr, csr_src, csr_w, Wt2 + (size_t)2 * 64 * 32, nullptr);
    {
        _Float16 *q0 = Ta, *q1 = Tb, *q2 = Tc;
        for (int k = 3; k < 25; ++k) {
            cheb_kernel<32, 64, false><<<NNODE, 256, 0, stream>>>(
                q0, q1, q2, OUT2, cptr, csr_src, csr_w, Wt2 + (size_t)k * 64 * 32, nullptr);
            _Float16* t = q0; q0 = q1; q1 = q2; q2 = t;
        }
    }

    relu_tr_kernel<<<(NNODE * NBATCH * G2D) / 256, 256, 0, stream>>>(OUT2, Hflat);
    fc1_kernel<<<128 * 32, 512, 0, stream>>>(Hflat, fc1w, partial);
    fc1_reduce_kernel<<<32, 256, 0, stream>>>(partial, fc1b, h1);
    fc2_kernel<<<1, 1024, 0, stream>>>(h1, fc2w, fc2b, out);
}

// Round 4
// 1686.794 us; speedup vs baseline: 2.8491x; 1.2418x over previous
//
#include <hip/hip_runtime.h>
#include <hip/hip_bf16.h>

typedef _Float16 f16x2 __attribute__((ext_vector_type(2)));
typedef _Float16 f16x4 __attribute__((ext_vector_type(4)));
typedef _Float16 f16x8 __attribute__((ext_vector_type(8)));
typedef float f32x4 __attribute__((ext_vector_type(4)));

static constexpr int NNODE = 8192;
static constexpr int NEDGE = 262144;
static constexpr int NBATCH = 16;
static constexpr int TDIM = 15;
static constexpr int G1D = 32;
static constexpr int G2D = 64;
static constexpr int NK = 25;
static constexpr size_t NG2 = (size_t)NNODE * G2D;        // 524288
static constexpr size_t ROWDW = 128;                      // dwords per stored node-row (256 halfs)
static constexpr size_t SLICE = (size_t)NNODE * ROWDW;    // f16x2 units per T-slice (4.19 MB)

// ---------------- graph preprocessing ----------------

__global__ void deg_cnt_kernel(const int* __restrict__ ei, int* __restrict__ deg,
                               int* __restrict__ cnt) {
    int e = blockIdx.x * 256 + threadIdx.x;
    if (e < NEDGE) {
        atomicAdd(&deg[ei[e]], 1);           // row (out-degree per reference)
        atomicAdd(&cnt[ei[NEDGE + e]], 1);   // col (CSR bucket counts)
    }
}

__global__ void dinv_kernel(const int* __restrict__ deg, float* __restrict__ dinv) {
    int n = blockIdx.x * 256 + threadIdx.x;
    if (n < NNODE) dinv[n] = (deg[n] > 0) ? rsqrtf((float)deg[n]) : 0.f;
}

__global__ __launch_bounds__(1024) void scan_kernel(const int* __restrict__ cnt,
                                                    int* __restrict__ ptr) {
    __shared__ int s[1024];
    int t = threadIdx.x;
    int base = t * 8;
    int loc[8];
    int sum = 0;
#pragma unroll
    for (int i = 0; i < 8; ++i) { loc[i] = sum; sum += cnt[base + i]; }
    s[t] = sum;
    __syncthreads();
    for (int off = 1; off < 1024; off <<= 1) {
        int v = (t >= off) ? s[t - off] : 0;
        __syncthreads();
        s[t] += v;
        __syncthreads();
    }
    int prev = (t > 0) ? s[t - 1] : 0;
#pragma unroll
    for (int i = 0; i < 8; ++i) ptr[base + i] = prev + loc[i];
    if (t == 1023) ptr[NNODE] = s[1023];
}

__global__ void fill_kernel(const int* __restrict__ ei, const int* __restrict__ ptr,
                            int* __restrict__ fill, const float* __restrict__ dinv,
                            int* __restrict__ csr_src, float* __restrict__ csr_w) {
    int e = blockIdx.x * 256 + threadIdx.x;
    if (e < NEDGE) {
        int r = ei[e], c = ei[NEDGE + e];
        int pos = ptr[c] + atomicAdd(&fill[c], 1);
        csr_src[pos] = r;
        csr_w[pos] = -dinv[r] * dinv[c];
    }
}

// ---------------- FFT (real part = cosine transform), fp16, padded F=16 ----------------
// Tall1[0][n][b*16 + f], f=15 column zero.

__global__ __launch_bounds__(256) void fft_kernel(const float* __restrict__ x,
                                                  _Float16* __restrict__ T0) {
    int n = blockIdx.x;
    __shared__ float xl[NBATCH][TDIM];
    __shared__ float ct[TDIM][TDIM];
    int t = threadIdx.x;
    if (t < NBATCH * TDIM) {
        int b = t / TDIM, s = t % TDIM;
        xl[b][s] = x[((size_t)b * NNODE + n) * TDIM + s];
    }
    if (t < TDIM * TDIM) {
        int tt = t / TDIM, s = t % TDIM;
        ct[tt][s] = cosf(6.283185307179586f * (float)((tt * s) % TDIM) / 15.0f);
    }
    __syncthreads();
    int b = t >> 4, f = t & 15;
    float a = 0.f;
    if (f < TDIM) {
#pragma unroll
        for (int s = 0; s < TDIM; ++s) a += xl[b][s] * ct[f][s];
    }
    T0[(size_t)n * 256 + t] = (_Float16)a;
}

// ---------------- W^T fp16 (zero-padded K=32): Wt[k][g][f0..31] ----------------

__global__ void wt_kernel(const float* __restrict__ W, _Float16* __restrict__ Wt,
                          int F, int G, int total) {
    int i = blockIdx.x * 256 + threadIdx.x;
    if (i < total) {
        int f = i & 31;
        int g = (i >> 5) % G;
        int k = i / (32 * G);
        float v = (f < F) ? W[((size_t)k * F + f) * G + g] : 0.f;
        Wt[i] = (_Float16)v;
    }
}

// ---------------- Chebyshev gather step (pure recursion, fp16 state) ----------------
// block = dest node c, 128 threads, each owns one dword of the 512-B row.
// FIRST: T1 = Lhat(T0). else: T2 = 2*Lhat(T1) - T0.

template <bool FIRST>
__global__ __launch_bounds__(128) void gather_step(
    const f16x2* __restrict__ Tsrc, const f16x2* __restrict__ T0,
    f16x2* __restrict__ T2, const int* __restrict__ cptr,
    const int* __restrict__ csrc, const float* __restrict__ cw) {
    __shared__ int es[128];
    __shared__ float ews[128];
    const int c = blockIdx.x;
    const int tid = threadIdx.x;

    float a0 = 0.f, a1 = 0.f;
    const int p0 = cptr[c], p1 = cptr[c + 1];
    for (int tb = p0; tb < p1; tb += 128) {
        int m = p1 - tb;
        if (m > 128) m = 128;
        __syncthreads();
        if (tid < m) { es[tid] = csrc[tb + tid]; ews[tid] = cw[tb + tid]; }
        __syncthreads();
        int j = 0;
        for (; j + 4 <= m; j += 4) {
            int s0 = es[j], s1 = es[j + 1], s2 = es[j + 2], s3 = es[j + 3];
            float w0 = ews[j], w1 = ews[j + 1], w2 = ews[j + 2], w3 = ews[j + 3];
            f16x2 r0 = Tsrc[(size_t)s0 * ROWDW + tid];
            f16x2 r1 = Tsrc[(size_t)s1 * ROWDW + tid];
            f16x2 r2 = Tsrc[(size_t)s2 * ROWDW + tid];
            f16x2 r3 = Tsrc[(size_t)s3 * ROWDW + tid];
            a0 += w0 * (float)r0[0]; a1 += w0 * (float)r0[1];
            a0 += w1 * (float)r1[0]; a1 += w1 * (float)r1[1];
            a0 += w2 * (float)r2[0]; a1 += w2 * (float)r2[1];
            a0 += w3 * (float)r3[0]; a1 += w3 * (float)r3[1];
        }
        for (; j < m; ++j) {
            int s = es[j]; float w = ews[j];
            f16x2 r = Tsrc[(size_t)s * ROWDW + tid];
            a0 += w * (float)r[0]; a1 += w * (float)r[1];
        }
    }

    f16x2 o;
    if (FIRST) {
        o[0] = (_Float16)a0; o[1] = (_Float16)a1;
    } else {
        f16x2 t0v = T0[(size_t)c * ROWDW + tid];
        o[0] = (_Float16)(2.f * a0 - (float)t0v[0]);
        o[1] = (_Float16)(2.f * a1 - (float)t0v[1]);
    }
    T2[(size_t)c * ROWDW + tid] = o;
}

// ---------------- deferred projection: OUT[n] = relu(bias + sum_k T_k[n] @ W_k) ----------------
// FDW: dwords per batch-row in the stored slice (8 for conv1 F=16-padded, 16 for conv2 half).
// MODE 0 (conv1): source Tall1 [k][n][128dw], dest = conv2 T0 as [h][n][256 halfs] fp16.
// MODE 1 (conv2): source Tall2 [k][h][n][128dw], dest = Hflat fp16 [b][n*64+g].

template <int FDW, int G, int MODE>
__global__ __launch_bounds__(G * 4) void proj_kernel(
    const unsigned int* __restrict__ Tall, const _Float16* __restrict__ Wt,
    const float* __restrict__ bias, _Float16* __restrict__ dest) {
    constexpr int STRIDE = NK * 32 + 8;   // 808 halfs, pad vs bank conflicts
    constexpr int NT = G * 4;
    __shared__ _Float16 A[16 * STRIDE];
    unsigned int* Adw = reinterpret_cast<unsigned int*>(A);

    const int n = blockIdx.x;
    const int tid = threadIdx.x;

    for (int i = tid; i < 16 * STRIDE / 2; i += NT) Adw[i] = 0u;
    __syncthreads();

    for (int idx = tid; idx < NK * 16 * FDW; idx += NT) {
        int k = idx / (16 * FDW);
        int r = idx % (16 * FDW);
        int b = r / FDW;
        int jp = r % FDW;
        size_t src;
        if (MODE == 0) {
            src = (size_t)k * SLICE + (size_t)n * ROWDW + b * FDW + jp;
        } else {
            src = (size_t)(k * 2 + (b >> 3)) * SLICE + (size_t)n * ROWDW + (b & 7) * FDW + jp;
        }
        Adw[b * (STRIDE / 2) + k * 16 + jp] = Tall[src];
    }
    __syncthreads();

    const int wv = tid >> 6, lane = tid & 63;
    const int m0 = lane & 15;        // A row index AND B/D col index
    const int krow = lane >> 4;
    const int k0 = krow * 8;
    const int g = wv * 16 + m0;

    const float bb = bias[g];
    f32x4 d = (f32x4){bb, bb, bb, bb};
#pragma unroll
    for (int k = 0; k < NK; ++k) {
        f16x8 af = *reinterpret_cast<const f16x8*>(&A[m0 * STRIDE + k * 32 + k0]);
        f16x8 bf = *reinterpret_cast<const f16x8*>(&Wt[((size_t)k * G + g) * 32 + k0]);
        d = __builtin_amdgcn_mfma_f32_16x16x32_f16(af, bf, d, 0, 0, 0);
    }
#pragma unroll
    for (int r = 0; r < 4; ++r) {
        int b = krow * 4 + r;
        _Float16 v = (_Float16)fmaxf(d[r], 0.f);
        if (MODE == 0) {
            // conv2 T0, half-split layout [h][n][ (b&7)*32 + g ]
            dest[((size_t)(b >> 3) * NNODE + n) * 256 + (b & 7) * 32 + g] = v;
        } else {
            // Hflat fp16 [b][n*64+g]
            dest[(size_t)b * NG2 + (size_t)n * G2D + g] = v;
        }
    }
}

// ---------------- fc ----------------

// grid = 128 chunks * 32 cgroups; block = 512 (8 waves); wave handles 2 c's.
__global__ __launch_bounds__(512) void fc1_kernel(const _Float16* __restrict__ Hflat,
                                                  const float* __restrict__ fc1w,
                                                  float* __restrict__ partial) {
    int wave = threadIdx.x >> 6, lane = threadIdx.x & 63;
    int chunk = blockIdx.x & 127, cg = blockIdx.x >> 7;
    int c0 = (cg * 8 + wave) * 2;
    const float* w0 = fc1w + (size_t)c0 * NG2 + (size_t)chunk * 4096;
    const float* w1 = w0 + NG2;
    const _Float16* h = Hflat + (size_t)chunk * 4096;
    float a0[16], a1[16];
#pragma unroll
    for (int b = 0; b < 16; ++b) { a0[b] = 0.f; a1[b] = 0.f; }
    for (int it = 0; it < 16; ++it) {
        int j = it * 256 + lane * 4;
        float4 wv0 = *reinterpret_cast<const float4*>(w0 + j);
        float4 wv1 = *reinterpret_cast<const float4*>(w1 + j);
#pragma unroll
        for (int b = 0; b < 16; ++b) {
            f16x4 hv = *reinterpret_cast<const f16x4*>(h + (size_t)b * NG2 + j);
            float h0 = (float)hv[0], h1 = (float)hv[1], h2 = (float)hv[2], h3 = (float)hv[3];
            a0[b] += wv0.x * h0 + wv0.y * h1 + wv0.z * h2 + wv0.w * h3;
            a1[b] += wv1.x * h0 + wv1.y * h1 + wv1.z * h2 + wv1.w * h3;
        }
    }
#pragma unroll
    for (int b = 0; b < 16; ++b) {
        float v0 = a0[b], v1 = a1[b];
        for (int off = 32; off; off >>= 1) {
            v0 += __shfl_down(v0, off);
            v1 += __shfl_down(v1, off);
        }
        if (lane == 0) {
            partial[((size_t)chunk * 512 + c0) * 16 + b] = v0;
            partial[((size_t)chunk * 512 + c0 + 1) * 16 + b] = v1;
        }
    }
}

__global__ void fc1_reduce_kernel(const float* __restrict__ partial,
                                  const float* __restrict__ fc1b, float* __restrict__ h1) {
    int i = blockIdx.x * 256 + threadIdx.x;  // 512*16
    if (i < 512 * 16) {
        int b = i & 15, c = i >> 4;
        float s = fc1b[c];
        for (int ch = 0; ch < 128; ++ch) s += partial[((size_t)ch * 512 + c) * 16 + b];
        h1[b * 512 + c] = s;
    }
}

__global__ __launch_bounds__(1024) void fc2_kernel(const float* __restrict__ h1,
                                                   const float* __restrict__ fc2w,
                                                   const float* __restrict__ fc2b,
                                                   float* __restrict__ out) {
    __shared__ float z[16][8];
    int wave = threadIdx.x >> 6, lane = threadIdx.x & 63;  // wave = b
    for (int d = 0; d < 6; ++d) {
        float acc = 0.f;
        for (int c = lane; c < 512; c += 64) acc += h1[wave * 512 + c] * fc2w[d * 512 + c];
        for (int off = 32; off; off >>= 1) acc += __shfl_down(acc, off);
        if (lane == 0) z[wave][d] = acc + fc2b[d];
    }
    __syncthreads();
    int t = threadIdx.x;
    if (t < 96) {
        int b = t / 6, d = t % 6;
        float m = z[b][0];
#pragma unroll
        for (int j = 1; j < 6; ++j) m = fmaxf(m, z[b][j]);
        float se = 0.f;
#pragma unroll
        for (int j = 0; j < 6; ++j) se += expf(z[b][j] - m);
        out[b * 6 + d] = z[b][d] - m - logf(se);
    }
}

// ---------------- host ----------------

extern "C" void kernel_launch(void* const* d_in, const int* in_sizes, int n_in,
                              void* d_out, int out_size, void* d_ws, size_t ws_size,
                              hipStream_t stream) {
    const float* x = (const float*)d_in[0];
    const int* ei = (const int*)d_in[1];
    const float* W1 = (const float*)d_in[2];
    const float* b1 = (const float*)d_in[3];
    const float* W2 = (const float*)d_in[4];
    const float* b2 = (const float*)d_in[5];
    const float* fc1w = (const float*)d_in[6];
    const float* fc1b = (const float*)d_in[7];
    const float* fc2w = (const float*)d_in[8];
    const float* fc2b = (const float*)d_in[9];
    float* out = (float*)d_out;

    char* ws = (char*)d_ws;
    size_t o = 0;
    auto alloc = [&](size_t bytes) -> void* {
        void* p = ws + o;
        o += (bytes + 255) & ~(size_t)255;
        return p;
    };
    // T_k storage: fp16 rows of 256 halfs (512 B)
    f16x2* Tall1 = (f16x2*)alloc(NK * SLICE * 4);          // 104.9 MB: [k][n][128dw]
    f16x2* Tall2 = (f16x2*)alloc(NK * 2 * SLICE * 4);      // 209.7 MB: [k][h][n][128dw]
    _Float16* Hflat = (_Float16*)alloc(NBATCH * NG2 * 2);  // 16.8 MB
    float* partial = (float*)alloc((size_t)128 * 512 * 16 * 4);
    int* deg = (int*)alloc(3 * NNODE * 4);
    int* cnt = deg + NNODE;
    int* fill = cnt + NNODE;
    int* cptr = (int*)alloc((NNODE + 8) * 4);
    float* dinv = (float*)alloc(NNODE * 4);
    int* csr_src = (int*)alloc((size_t)NEDGE * 4);
    float* csr_w = (float*)alloc((size_t)NEDGE * 4);
    _Float16* Wt1 = (_Float16*)alloc(NK * G1D * 32 * 2);
    _Float16* Wt2 = (_Float16*)alloc(NK * G2D * 32 * 2);
    float* h1 = (float*)alloc(16 * 512 * 4);

    hipMemsetAsync(deg, 0, 3 * NNODE * 4, stream);
    deg_cnt_kernel<<<NEDGE / 256, 256, 0, stream>>>(ei, deg, cnt);
    dinv_kernel<<<NNODE / 256, 256, 0, stream>>>(deg, dinv);
    scan_kernel<<<1, 1024, 0, stream>>>(cnt, cptr);
    fill_kernel<<<NEDGE / 256, 256, 0, stream>>>(ei, cptr, fill, dinv, csr_src, csr_w);
    fft_kernel<<<NNODE, 256, 0, stream>>>(x, (_Float16*)Tall1);
    wt_kernel<<<(NK * G1D * 32 + 255) / 256, 256, 0, stream>>>(W1, Wt1, 15, G1D,
                                                               NK * G1D * 32);
    wt_kernel<<<(NK * G2D * 32 + 255) / 256, 256, 0, stream>>>(W2, Wt2, 32, G2D,
                                                               NK * G2D * 32);

    // conv1 recursion: Tall1[k] from Tall1[k-1], Tall1[k-2]
    gather_step<true><<<NNODE, 128, 0, stream>>>(Tall1, nullptr, Tall1 + SLICE, cptr,
                                                 csr_src, csr_w);
    for (int k = 2; k < NK; ++k) {
        gather_step<false><<<NNODE, 128, 0, stream>>>(
            Tall1 + (size_t)(k - 1) * SLICE, Tall1 + (size_t)(k - 2) * SLICE,
            Tall1 + (size_t)k * SLICE, cptr, csr_src, csr_w);
    }
    // proj1: writes relu'd fp16 into Tall2[k=0] (both halves)
    proj_kernel<8, G1D, 0><<<NNODE, G1D * 4, 0, stream>>>(
        (const unsigned int*)Tall1, Wt1, b1, (_Float16*)Tall2);

    // conv2 recursion, per batch-half (working set 4 MB -> per-XCD L2)
    for (int h = 0; h < 2; ++h) {
        gather_step<true><<<NNODE, 128, 0, stream>>>(
            Tall2 + (size_t)h * SLICE, nullptr, Tall2 + (size_t)(2 + h) * SLICE, cptr,
            csr_src, csr_w);
        for (int k = 2; k < NK; ++k) {
            gather_step<false><<<NNODE, 128, 0, stream>>>(
                Tall2 + (size_t)((k - 1) * 2 + h) * SLICE,
                Tall2 + (size_t)((k - 2) * 2 + h) * SLICE,
                Tall2 + (size_t)(k * 2 + h) * SLICE, cptr, csr_src, csr_w);
        }
    }
    // proj2: writes relu'd fp16 Hflat directly
    proj_kernel<16, G2D, 1><<<NNODE, G2D * 4, 0, stream>>>(
        (const unsigned int*)Tall2, Wt2, b2, Hflat);

    fc1_kernel<<<128 * 32, 512, 0, stream>>>(Hflat, fc1w, partial);
    fc1_reduce_kernel<<<32, 256, 0, stream>>>(partial, fc1b, h1);
    fc2_kernel<<<1, 1024, 0, stream>>>(h1, fc2w, fc2b, out);
}

// Round 5
// 1529.494 us; speedup vs baseline: 3.1421x; 1.1028x over previous
//
#include <hip/hip_runtime.h>
#include <hip/hip_bf16.h>

typedef _Float16 f16x2 __attribute__((ext_vector_type(2)));
typedef _Float16 f16x4 __attribute__((ext_vector_type(4)));
typedef _Float16 f16x8 __attribute__((ext_vector_type(8)));
typedef float f32x4 __attribute__((ext_vector_type(4)));

static constexpr int NNODE = 8192;
static constexpr int NEDGE = 262144;
static constexpr int NBATCH = 16;
static constexpr int TDIM = 15;
static constexpr int G1D = 32;
static constexpr int G2D = 64;
static constexpr int NK = 25;
static constexpr size_t NG2 = (size_t)NNODE * G2D;      // 524288
// slice row = 128 halfs = 64 dwords = 256 B
static constexpr size_t SROW = 64;                      // f16x2 per row
static constexpr size_t SLICE = (size_t)NNODE * SROW;   // f16x2 per slice (2.1 MB)

// ---------------- graph preprocessing ----------------

__global__ void deg_cnt_kernel(const int* __restrict__ ei, int* __restrict__ deg,
                               int* __restrict__ cnt) {
    int e = blockIdx.x * 256 + threadIdx.x;
    if (e < NEDGE) {
        atomicAdd(&deg[ei[e]], 1);           // row (out-degree per reference)
        atomicAdd(&cnt[ei[NEDGE + e]], 1);   // col (CSR bucket counts)
    }
}

__global__ void dinv_kernel(const int* __restrict__ deg, float* __restrict__ dinv) {
    int n = blockIdx.x * 256 + threadIdx.x;
    if (n < NNODE) dinv[n] = (deg[n] > 0) ? rsqrtf((float)deg[n]) : 0.f;
}

__global__ __launch_bounds__(1024) void scan_kernel(const int* __restrict__ cnt,
                                                    int* __restrict__ ptr) {
    __shared__ int s[1024];
    int t = threadIdx.x;
    int base = t * 8;
    int loc[8];
    int sum = 0;
#pragma unroll
    for (int i = 0; i < 8; ++i) { loc[i] = sum; sum += cnt[base + i]; }
    s[t] = sum;
    __syncthreads();
    for (int off = 1; off < 1024; off <<= 1) {
        int v = (t >= off) ? s[t - off] : 0;
        __syncthreads();
        s[t] += v;
        __syncthreads();
    }
    int prev = (t > 0) ? s[t - 1] : 0;
#pragma unroll
    for (int i = 0; i < 8; ++i) ptr[base + i] = prev + loc[i];
    if (t == 1023) ptr[NNODE] = s[1023];
}

__global__ void fill_kernel(const int* __restrict__ ei, const int* __restrict__ ptr,
                            int* __restrict__ fill, const float* __restrict__ dinv,
                            int* __restrict__ csr_src, float* __restrict__ csr_w) {
    int e = blockIdx.x * 256 + threadIdx.x;
    if (e < NEDGE) {
        int r = ei[e], c = ei[NEDGE + e];
        int pos = ptr[c] + atomicAdd(&fill[c], 1);
        csr_src[pos] = r;
        csr_w[pos] = -dinv[r] * dinv[c];
    }
}

// ---------------- FFT (real part = cosine transform) -> Tall1 k=0 slices ----------------
// slice h (batches h*8..h*8+7), row layout: (b&7)*16 + f (f padded to 16, f=15 zero)

__global__ __launch_bounds__(256) void fft_kernel(const float* __restrict__ x,
                                                  _Float16* __restrict__ T0) {
    int n = blockIdx.x;
    __shared__ float xl[NBATCH][TDIM];
    __shared__ float ct[TDIM][TDIM];
    int t = threadIdx.x;
    if (t < NBATCH * TDIM) {
        int b = t / TDIM, s = t % TDIM;
        xl[b][s] = x[((size_t)b * NNODE + n) * TDIM + s];
    }
    if (t < TDIM * TDIM) {
        int tt = t / TDIM, s = t % TDIM;
        ct[tt][s] = cosf(6.283185307179586f * (float)((tt * s) % TDIM) / 15.0f);
    }
    __syncthreads();
    int b = t >> 4, f = t & 15;
    float a = 0.f;
    if (f < TDIM) {
#pragma unroll
        for (int s = 0; s < TDIM; ++s) a += xl[b][s] * ct[f][s];
    }
    T0[((size_t)(b >> 3) * NNODE + n) * 128 + (b & 7) * 16 + f] = (_Float16)a;
}

// ---------------- W^T fp16 (zero-padded K=32): Wt[k][g][f0..31] ----------------

__global__ void wt_kernel(const float* __restrict__ W, _Float16* __restrict__ Wt,
                          int F, int G, int total) {
    int i = blockIdx.x * 256 + threadIdx.x;
    if (i < total) {
        int f = i & 31;
        int g = (i >> 5) % G;
        int k = i / (32 * G);
        float v = (f < F) ? W[((size_t)k * F + f) * G + g] : 0.f;
        Wt[i] = (_Float16)v;
    }
}

// ---------------- Chebyshev gather step, XCD-sharded slices ----------------
// Q slices of 256-B rows. blockIdx%8 -> XCD (heuristic): each XCD owns ONE slice
// so its gather working set (2.1 MB slice + its CSR share) stays L2-resident.
// One wave per (node, slice); lane owns one dword of the row. Edge idx/weight
// broadcast via readlane -> scalar-base row loads. No LDS, no barriers.

template <int Q, bool FIRST>
__global__ __launch_bounds__(256, 8) void gather_step(
    const f16x2* __restrict__ Tsrc, const f16x2* __restrict__ Tprev0,
    f16x2* __restrict__ Tdst, const int* __restrict__ cptr,
    const int* __restrict__ csrc, const float* __restrict__ cw) {
    constexpr int CH = 8 / Q;                 // XCDs per slice
    const int bid = blockIdx.x;
    const int xcd = bid & 7;
    const int s = xcd / CH;
    const int chunk = xcd % CH;
    const int wv = threadIdx.x >> 6, lane = threadIdx.x & 63;
    const int node = (chunk * (256 * Q) + (bid >> 3)) * 4 + wv;

    const f16x2* __restrict__ src = Tsrc + (size_t)s * SLICE;
    float a0 = 0.f, a1 = 0.f;
    const int p0 = cptr[node], p1 = cptr[node + 1];
    for (int tb = p0; tb < p1; tb += 64) {
        int m = p1 - tb;
        if (m > 64) m = 64;
        const bool ok = lane < m;
        int esrc = ok ? csrc[tb + lane] : 0;
        unsigned int ewu = ok ? __float_as_uint(cw[tb + lane]) : 0u;
        int j = 0;
        for (; j + 4 <= m; j += 4) {
            int s0 = __builtin_amdgcn_readlane(esrc, j);
            int s1 = __builtin_amdgcn_readlane(esrc, j + 1);
            int s2 = __builtin_amdgcn_readlane(esrc, j + 2);
            int s3 = __builtin_amdgcn_readlane(esrc, j + 3);
            float w0 = __uint_as_float(__builtin_amdgcn_readlane(ewu, j));
            float w1 = __uint_as_float(__builtin_amdgcn_readlane(ewu, j + 1));
            float w2 = __uint_as_float(__builtin_amdgcn_readlane(ewu, j + 2));
            float w3 = __uint_as_float(__builtin_amdgcn_readlane(ewu, j + 3));
            f16x2 r0 = src[(size_t)s0 * SROW + lane];
            f16x2 r1 = src[(size_t)s1 * SROW + lane];
            f16x2 r2 = src[(size_t)s2 * SROW + lane];
            f16x2 r3 = src[(size_t)s3 * SROW + lane];
            a0 += w0 * (float)r0[0]; a1 += w0 * (float)r0[1];
            a0 += w1 * (float)r1[0]; a1 += w1 * (float)r1[1];
            a0 += w2 * (float)r2[0]; a1 += w2 * (float)r2[1];
            a0 += w3 * (float)r3[0]; a1 += w3 * (float)r3[1];
        }
        for (; j < m; ++j) {
            int sj = __builtin_amdgcn_readlane(esrc, j);
            float wj = __uint_as_float(__builtin_amdgcn_readlane(ewu, j));
            f16x2 r = src[(size_t)sj * SROW + lane];
            a0 += wj * (float)r[0]; a1 += wj * (float)r[1];
        }
    }

    f16x2 o;
    if (FIRST) {
        o[0] = (_Float16)a0; o[1] = (_Float16)a1;
    } else {
        f16x2 t0 = (Tprev0 + (size_t)s * SLICE)[(size_t)node * SROW + lane];
        o[0] = (_Float16)(2.f * a0 - (float)t0[0]);
        o[1] = (_Float16)(2.f * a1 - (float)t0[1]);
    }
    (Tdst + (size_t)s * SLICE)[(size_t)node * SROW + lane] = o;
}

// ---------------- deferred projections ----------------
// proj1: conv1 Tall1 [k][h][n][64dw] -> relu(bias + sum_k T_k @ W1_k) -> Tall2 k=0
//        quarter-slice layout [q][n][bl2*32+g], b = q*4+bl2.

__global__ __launch_bounds__(128) void proj1_kernel(
    const unsigned int* __restrict__ Tall, const _Float16* __restrict__ Wt,
    const float* __restrict__ bias, _Float16* __restrict__ dest) {
    constexpr int STRIDE = NK * 32 + 8;   // 808 halfs
    __shared__ _Float16 A[16 * STRIDE];
    unsigned int* Adw = reinterpret_cast<unsigned int*>(A);
    const int n = blockIdx.x;
    const int tid = threadIdx.x;

    for (int i = tid; i < 16 * STRIDE / 2; i += 128) Adw[i] = 0u;
    __syncthreads();
    for (int idx = tid; idx < NK * 128; idx += 128) {
        int k = idx >> 7, r = idx & 127;
        int h = r >> 6, j = r & 63;
        int bl = j >> 3, jp = j & 7;
        int b = h * 8 + bl;
        Adw[b * (STRIDE / 2) + k * 16 + jp] =
            Tall[((size_t)(k * 2 + h) * NNODE + n) * 64 + j];
    }
    __syncthreads();

    const int wv = tid >> 6, lane = tid & 63;
    const int m0 = lane & 15;
    const int krow = lane >> 4;
    const int k0 = krow * 8;
    const int g = wv * 16 + m0;
    const float bb = bias[g];
    f32x4 d = (f32x4){bb, bb, bb, bb};
#pragma unroll
    for (int k = 0; k < NK; ++k) {
        f16x8 af = *reinterpret_cast<const f16x8*>(&A[m0 * STRIDE + k * 32 + k0]);
        f16x8 bf = *reinterpret_cast<const f16x8*>(&Wt[((size_t)k * G1D + g) * 32 + k0]);
        d = __builtin_amdgcn_mfma_f32_16x16x32_f16(af, bf, d, 0, 0, 0);
    }
#pragma unroll
    for (int r = 0; r < 4; ++r) {
        int b = krow * 4 + r;
        _Float16 v = (_Float16)fmaxf(d[r], 0.f);
        dest[((size_t)(b >> 2) * NNODE + n) * 128 + (b & 3) * 32 + g] = v;
    }
}

// proj2: conv2 Tall2 [k][q][n][64dw] -> relu -> fp16 Hflat [b][n*64+g]

__global__ __launch_bounds__(256) void proj2_kernel(
    const unsigned int* __restrict__ Tall, const _Float16* __restrict__ Wt,
    const float* __restrict__ bias, _Float16* __restrict__ dest) {
    constexpr int STRIDE = NK * 32 + 8;
    __shared__ _Float16 A[16 * STRIDE];
    unsigned int* Adw = reinterpret_cast<unsigned int*>(A);
    const int n = blockIdx.x;
    const int tid = threadIdx.x;

    for (int i = tid; i < 16 * STRIDE / 2; i += 256) Adw[i] = 0u;
    __syncthreads();
    for (int idx = tid; idx < NK * 256; idx += 256) {
        int k = idx >> 8, r = idx & 255;
        int q = r >> 6, j = r & 63;
        int bl2 = j >> 4, jp = j & 15;
        int b = q * 4 + bl2;
        Adw[b * (STRIDE / 2) + k * 16 + jp] =
            Tall[((size_t)(k * 4 + q) * NNODE + n) * 64 + j];
    }
    __syncthreads();

    const int wv = tid >> 6, lane = tid & 63;
    const int m0 = lane & 15;
    const int krow = lane >> 4;
    const int k0 = krow * 8;
    const int g = wv * 16 + m0;
    const float bb = bias[g];
    f32x4 d = (f32x4){bb, bb, bb, bb};
#pragma unroll
    for (int k = 0; k < NK; ++k) {
        f16x8 af = *reinterpret_cast<const f16x8*>(&A[m0 * STRIDE + k * 32 + k0]);
        f16x8 bf = *reinterpret_cast<const f16x8*>(&Wt[((size_t)k * G2D + g) * 32 + k0]);
        d = __builtin_amdgcn_mfma_f32_16x16x32_f16(af, bf, d, 0, 0, 0);
    }
#pragma unroll
    for (int r = 0; r < 4; ++r) {
        int b = krow * 4 + r;
        _Float16 v = (_Float16)fmaxf(d[r], 0.f);
        dest[(size_t)b * NG2 + (size_t)n * G2D + g] = v;
    }
}

// ---------------- fc ----------------

__global__ __launch_bounds__(512) void fc1_kernel(const _Float16* __restrict__ Hflat,
                                                  const float* __restrict__ fc1w,
                                                  float* __restrict__ partial) {
    int wave = threadIdx.x >> 6, lane = threadIdx.x & 63;
    int chunk = blockIdx.x & 127, cg = blockIdx.x >> 7;
    int c0 = (cg * 8 + wave) * 2;
    const float* w0 = fc1w + (size_t)c0 * NG2 + (size_t)chunk * 4096;
    const float* w1 = w0 + NG2;
    const _Float16* h = Hflat + (size_t)chunk * 4096;
    float a0[16], a1[16];
#pragma unroll
    for (int b = 0; b < 16; ++b) { a0[b] = 0.f; a1[b] = 0.f; }
    for (int it = 0; it < 16; ++it) {
        int j = it * 256 + lane * 4;
        float4 wv0 = *reinterpret_cast<const float4*>(w0 + j);
        float4 wv1 = *reinterpret_cast<const float4*>(w1 + j);
#pragma unroll
        for (int b = 0; b < 16; ++b) {
            f16x4 hv = *reinterpret_cast<const f16x4*>(h + (size_t)b * NG2 + j);
            float h0 = (float)hv[0], h1 = (float)hv[1], h2 = (float)hv[2], h3 = (float)hv[3];
            a0[b] += wv0.x * h0 + wv0.y * h1 + wv0.z * h2 + wv0.w * h3;
            a1[b] += wv1.x * h0 + wv1.y * h1 + wv1.z * h2 + wv1.w * h3;
        }
    }
#pragma unroll
    for (int b = 0; b < 16; ++b) {
        float v0 = a0[b], v1 = a1[b];
        for (int off = 32; off; off >>= 1) {
            v0 += __shfl_down(v0, off);
            v1 += __shfl_down(v1, off);
        }
        if (lane == 0) {
            partial[((size_t)chunk * 512 + c0) * 16 + b] = v0;
            partial[((size_t)chunk * 512 + c0 + 1) * 16 + b] = v1;
        }
    }
}

__global__ void fc1_reduce_kernel(const float* __restrict__ partial,
                                  const float* __restrict__ fc1b, float* __restrict__ h1) {
    int i = blockIdx.x * 256 + threadIdx.x;  // 512*16
    if (i < 512 * 16) {
        int b = i & 15, c = i >> 4;
        float s = fc1b[c];
        for (int ch = 0; ch < 128; ++ch) s += partial[((size_t)ch * 512 + c) * 16 + b];
        h1[b * 512 + c] = s;
    }
}

__global__ __launch_bounds__(1024) void fc2_kernel(const float* __restrict__ h1,
                                                   const float* __restrict__ fc2w,
                                                   const float* __restrict__ fc2b,
                                                   float* __restrict__ out) {
    __shared__ float z[16][8];
    int wave = threadIdx.x >> 6, lane = threadIdx.x & 63;  // wave = b
    for (int d = 0; d < 6; ++d) {
        float acc = 0.f;
        for (int c = lane; c < 512; c += 64) acc += h1[wave * 512 + c] * fc2w[d * 512 + c];
        for (int off = 32; off; off >>= 1) acc += __shfl_down(acc, off);
        if (lane == 0) z[wave][d] = acc + fc2b[d];
    }
    __syncthreads();
    int t = threadIdx.x;
    if (t < 96) {
        int b = t / 6, d = t % 6;
        float m = z[b][0];
#pragma unroll
        for (int j = 1; j < 6; ++j) m = fmaxf(m, z[b][j]);
        float se = 0.f;
#pragma unroll
        for (int j = 0; j < 6; ++j) se += expf(z[b][j] - m);
        out[b * 6 + d] = z[b][d] - m - logf(se);
    }
}

// ---------------- host ----------------

extern "C" void kernel_launch(void* const* d_in, const int* in_sizes, int n_in,
                              void* d_out, int out_size, void* d_ws, size_t ws_size,
                              hipStream_t stream) {
    const float* x = (const float*)d_in[0];
    const int* ei = (const int*)d_in[1];
    const float* W1 = (const float*)d_in[2];
    const float* b1 = (const float*)d_in[3];
    const float* W2 = (const float*)d_in[4];
    const float* b2 = (const float*)d_in[5];
    const float* fc1w = (const float*)d_in[6];
    const float* fc1b = (const float*)d_in[7];
    const float* fc2w = (const float*)d_in[8];
    const float* fc2b = (const float*)d_in[9];
    float* out = (float*)d_out;

    char* ws = (char*)d_ws;
    size_t o = 0;
    auto alloc = [&](size_t bytes) -> void* {
        void* p = ws + o;
        o += (bytes + 255) & ~(size_t)255;
        return p;
    };
    f16x2* Tall1 = (f16x2*)alloc(NK * 2 * SLICE * 4);      // 104.9 MB: [k][h][n][64dw]
    f16x2* Tall2 = (f16x2*)alloc(NK * 4 * SLICE * 4);      // 209.7 MB: [k][q][n][64dw]
    _Float16* Hflat = (_Float16*)alloc(NBATCH * NG2 * 2);  // 16.8 MB
    float* partial = (float*)alloc((size_t)128 * 512 * 16 * 4);
    int* deg = (int*)alloc(3 * NNODE * 4);
    int* cnt = deg + NNODE;
    int* fill = cnt + NNODE;
    int* cptr = (int*)alloc((NNODE + 8) * 4);
    float* dinv = (float*)alloc(NNODE * 4);
    int* csr_src = (int*)alloc((size_t)NEDGE * 4);
    float* csr_w = (float*)alloc((size_t)NEDGE * 4);
    _Float16* Wt1 = (_Float16*)alloc(NK * G1D * 32 * 2);
    _Float16* Wt2 = (_Float16*)alloc(NK * G2D * 32 * 2);
    float* h1 = (float*)alloc(16 * 512 * 4);

    hipMemsetAsync(deg, 0, 3 * NNODE * 4, stream);
    deg_cnt_kernel<<<NEDGE / 256, 256, 0, stream>>>(ei, deg, cnt);
    dinv_kernel<<<NNODE / 256, 256, 0, stream>>>(deg, dinv);
    scan_kernel<<<1, 1024, 0, stream>>>(cnt, cptr);
    fill_kernel<<<NEDGE / 256, 256, 0, stream>>>(ei, cptr, fill, dinv, csr_src, csr_w);
    fft_kernel<<<NNODE, 256, 0, stream>>>(x, (_Float16*)Tall1);
    wt_kernel<<<(NK * G1D * 32 + 255) / 256, 256, 0, stream>>>(W1, Wt1, 15, G1D,
                                                               NK * G1D * 32);
    wt_kernel<<<(NK * G2D * 32 + 255) / 256, 256, 0, stream>>>(W2, Wt2, 32, G2D,
                                                               NK * G2D * 32);

    // conv1 recursion: Q=2 slices, grid 4096x256 (one wave per node-slice)
    gather_step<2, true><<<4096, 256, 0, stream>>>(Tall1, nullptr, Tall1 + 2 * SLICE,
                                                   cptr, csr_src, csr_w);
    for (int k = 2; k < NK; ++k) {
        gather_step<2, false><<<4096, 256, 0, stream>>>(
            Tall1 + (size_t)(k - 1) * 2 * SLICE, Tall1 + (size_t)(k - 2) * 2 * SLICE,
            Tall1 + (size_t)k * 2 * SLICE, cptr, csr_src, csr_w);
    }
    proj1_kernel<<<NNODE, 128, 0, stream>>>((const unsigned int*)Tall1, Wt1, b1,
                                            (_Float16*)Tall2);

    // conv2 recursion: Q=4 slices, grid 8192x256
    gather_step<4, true><<<8192, 256, 0, stream>>>(Tall2, nullptr, Tall2 + 4 * SLICE,
                                                   cptr, csr_src, csr_w);
    for (int k = 2; k < NK; ++k) {
        gather_step<4, false><<<8192, 256, 0, stream>>>(
            Tall2 + (size_t)(k - 1) * 4 * SLICE, Tall2 + (size_t)(k - 2) * 4 * SLICE,
            Tall2 + (size_t)k * 4 * SLICE, cptr, csr_src, csr_w);
    }
    proj2_kernel<<<NNODE, 256, 0, stream>>>((const unsigned int*)Tall2, Wt2, b2, Hflat);

    fc1_kernel<<<128 * 32, 512, 0, stream>>>(Hflat, fc1w, partial);
    fc1_reduce_kernel<<<32, 256, 0, stream>>>(partial, fc1b, h1);
    fc2_kernel<<<1, 1024, 0, stream>>>(h1, fc2w, fc2b, out);
}